// Round 1
// baseline (803.652 us; speedup 1.0000x reference)
//
#include <hip/hip_runtime.h>

// 2-layer GRU (B=4096, S=512, IN=4, H=32) + FC(32->32) + FC(32->1), fp32 in/out.
// One wave per 16-batch group; MFMA 16x16x32 bf16 with hi/lo split operands
// (~fp32 accuracy); weights resident in registers/AGPRs; state via small LDS.

#define SEQ 512
#define LOG2E 1.44269504088896340736f

typedef __attribute__((ext_vector_type(8))) short  short8;
typedef __attribute__((ext_vector_type(4))) float  f32x4;
typedef __attribute__((ext_vector_type(2))) unsigned uint2v;

__device__ __forceinline__ unsigned short f2bf(float f) {
    unsigned u = __builtin_bit_cast(unsigned, f);
    return (unsigned short)((u + 0x7fffu + ((u >> 16) & 1u)) >> 16);
}
__device__ __forceinline__ float bf2f(unsigned short b) {
    return __builtin_bit_cast(float, ((unsigned)b) << 16);
}
__device__ __forceinline__ unsigned cvtpk(float a, float b) {
    unsigned r;
    asm("v_cvt_pk_bf16_f32 %0, %1, %2" : "=v"(r) : "v"(a), "v"(b));
    return r;
}
__device__ __forceinline__ float sigm(float x) {
    return __builtin_amdgcn_rcpf(1.0f + __builtin_amdgcn_exp2f(-LOG2E * x));
}
__device__ __forceinline__ float tanh_(float x) {
    return 1.0f - 2.0f * __builtin_amdgcn_rcpf(1.0f + __builtin_amdgcn_exp2f((2.0f * LOG2E) * x));
}

#define MFMA(A, B, C) __builtin_amdgcn_mfma_f32_16x16x32_bf16((A), (B), (C), 0, 0, 0)

__global__ __launch_bounds__(64, 1) void gru_fused(
    const float* __restrict__ x,
    const float* __restrict__ Wih0, const float* __restrict__ Whh0,
    const float* __restrict__ bih0, const float* __restrict__ bhh0,
    const float* __restrict__ Wih1, const float* __restrict__ Whh1,
    const float* __restrict__ bih1, const float* __restrict__ bhh1,
    const float* __restrict__ Wfc2, const float* __restrict__ bfc2,
    const float* __restrict__ Wfc,  const float* __restrict__ bfc,
    float* __restrict__ out)
{
    const int lane = threadIdx.x;   // 0..63 (single wave per block)
    const int c = lane & 15;        // tile row (gate) for A / batch col for B,D
    const int q = lane >> 4;        // 0..3
    const int b0 = blockIdx.x * 16;

    // LDS: h-state transport, [16 rows][32 bf16] padded to 80B rows. 4 buffers.
    __shared__ __align__(16) char smem[4 * 1280];
    char* S0HI = smem;
    char* S0LO = smem + 1280;
    char* S1HI = smem + 2560;
    char* S1LO = smem + 3840;

    // zero-init state buffers (h0 = 0)
#pragma unroll
    for (int i = 0; i < 20; ++i)
        ((unsigned*)smem)[lane + 64 * i] = 0u;

    // ---------------- weight fragments (A operand, loop-invariant) ----------
    // A-frag: lane holds W[16t + c][8q + e], e=0..7, as bf16 hi/lo split.
    short8 whh0h[6], whh0l[6], wih1h[6], wih1l[6], whh1h[6], whh1l[6];
    short8 wih0h[6], wih0l[6];

    {
        const float* Ws[3] = {Whh0, Wih1, Whh1};
        short8* Hs[3] = {whh0h, wih1h, whh1h};
        short8* Ls[3] = {whh0l, wih1l, whh1l};
#pragma unroll
        for (int m = 0; m < 3; ++m) {
#pragma unroll
            for (int t = 0; t < 6; ++t) {
                const float* p = Ws[m] + (16 * t + c) * 32 + 8 * q;
                f32x4 v0 = *(const f32x4*)p;
                f32x4 v1 = *(const f32x4*)(p + 4);
                short8 h8, l8;
#pragma unroll
                for (int e = 0; e < 8; ++e) {
                    float v = (e < 4) ? v0[e] : v1[e - 4];
                    unsigned short hb = f2bf(v);
                    h8[e] = (short)hb;
                    l8[e] = (short)f2bf(v - bf2f(hb));
                }
                Hs[m][t] = h8;
                Ls[m][t] = l8;
            }
        }
    }
    // W_ih0 is 96x4: only k<4 (q==0 lanes, e<4) nonzero.
#pragma unroll
    for (int t = 0; t < 6; ++t) {
        short8 h8 = {0, 0, 0, 0, 0, 0, 0, 0};
        short8 l8 = {0, 0, 0, 0, 0, 0, 0, 0};
        if (q == 0) {
            f32x4 v = *(const f32x4*)(Wih0 + (16 * t + c) * 4);
#pragma unroll
            for (int e = 0; e < 4; ++e) {
                unsigned short hb = f2bf(v[e]);
                h8[e] = (short)hb;
                l8[e] = (short)f2bf(v[e] - bf2f(hb));
            }
        }
        wih0h[t] = h8;
        wih0l[t] = l8;
    }

    // ---------------- bias accumulator inits (C operand) --------------------
    // D-layout: row (gate within tile) = 4q + r  -> bias[16t + 4q + r]
    f32x4 bx0[6], bh0[6], bx1[6], bh1[6];
#pragma unroll
    for (int t = 0; t < 6; ++t) {
        bx0[t] = *(const f32x4*)(bih0 + 16 * t + 4 * q);
        bh0[t] = *(const f32x4*)(bhh0 + 16 * t + 4 * q);
        bx1[t] = *(const f32x4*)(bih1 + 16 * t + 4 * q);
        bh1[t] = *(const f32x4*)(bhh1 + 16 * t + 4 * q);
    }

    // hidden states in fp32 regs: unit j = 16*tp + 4*q + r for batch c
    float hst0[2][4] = {{0, 0, 0, 0}, {0, 0, 0, 0}};
    float hst1[2][4] = {{0, 0, 0, 0}, {0, 0, 0, 0}};

    const float* xp = x + (long)(b0 + c) * (SEQ * 4);
    const int frag_off = c * 80 + q * 16;

#pragma unroll 1
    for (int s = 0; s < SEQ; ++s) {
        // ---- x fragment (B operand, k<4 nonzero on q==0 lanes) ----
        short8 xh = {0, 0, 0, 0, 0, 0, 0, 0};
        short8 xl = {0, 0, 0, 0, 0, 0, 0, 0};
        if (q == 0) {
            f32x4 xv = *(const f32x4*)(xp + 4 * s);
#pragma unroll
            for (int e = 0; e < 4; ++e) {
                unsigned short hb = f2bf(xv[e]);
                xh[e] = (short)hb;
                xl[e] = (short)f2bf(xv[e] - bf2f(hb));
            }
        }

        // ---- layer 0 ----
        short8 f0h = *(const short8*)(S0HI + frag_off);
        short8 f0l = *(const short8*)(S0LO + frag_off);

        f32x4 ax[6], ah[6];
#pragma unroll
        for (int t = 0; t < 6; ++t) {
            f32x4 a;
            a = MFMA(wih0h[t], xh, bx0[t]);
            a = MFMA(wih0l[t], xh, a);
            a = MFMA(wih0h[t], xl, a);
            ax[t] = a;
            f32x4 b;
            b = MFMA(whh0h[t], f0h, bh0[t]);
            b = MFMA(whh0l[t], f0h, b);
            b = MFMA(whh0h[t], f0l, b);
            ah[t] = b;
        }
#pragma unroll
        for (int tp = 0; tp < 2; ++tp) {
            float hv[4];
#pragma unroll
            for (int r = 0; r < 4; ++r) {
                float rg = sigm(ax[tp][r] + ah[tp][r]);
                float zg = sigm(ax[2 + tp][r] + ah[2 + tp][r]);
                float ng = tanh_(ax[4 + tp][r] + rg * ah[4 + tp][r]);
                float h = hst0[tp][r];
                float hN = ng + zg * (h - ng);
                hst0[tp][r] = hN;
                hv[r] = hN;
            }
            unsigned d0 = cvtpk(hv[0], hv[1]);
            unsigned d1 = cvtpk(hv[2], hv[3]);
            float g0 = bf2f((unsigned short)(d0 & 0xffffu));
            float g1 = bf2f((unsigned short)(d0 >> 16));
            float g2 = bf2f((unsigned short)(d1 & 0xffffu));
            float g3 = bf2f((unsigned short)(d1 >> 16));
            unsigned e0 = cvtpk(hv[0] - g0, hv[1] - g1);
            unsigned e1 = cvtpk(hv[2] - g2, hv[3] - g3);
            const int off = c * 80 + (16 * tp + 4 * q) * 2;
            uint2v wh = {d0, d1};
            uint2v wl = {e0, e1};
            *(uint2v*)(S0HI + off) = wh;
            *(uint2v*)(S0LO + off) = wl;
        }

        // ---- layer 1 (consumes freshly written state0 = h1[s]) ----
        short8 f1h = *(const short8*)(S0HI + frag_off);
        short8 f1l = *(const short8*)(S0LO + frag_off);
        short8 f2h = *(const short8*)(S1HI + frag_off);
        short8 f2l = *(const short8*)(S1LO + frag_off);

#pragma unroll
        for (int t = 0; t < 6; ++t) {
            f32x4 a;
            a = MFMA(wih1h[t], f1h, bx1[t]);
            a = MFMA(wih1l[t], f1h, a);
            a = MFMA(wih1h[t], f1l, a);
            ax[t] = a;
            f32x4 b;
            b = MFMA(whh1h[t], f2h, bh1[t]);
            b = MFMA(whh1l[t], f2h, b);
            b = MFMA(whh1h[t], f2l, b);
            ah[t] = b;
        }
#pragma unroll
        for (int tp = 0; tp < 2; ++tp) {
            float hv[4];
#pragma unroll
            for (int r = 0; r < 4; ++r) {
                float rg = sigm(ax[tp][r] + ah[tp][r]);
                float zg = sigm(ax[2 + tp][r] + ah[2 + tp][r]);
                float ng = tanh_(ax[4 + tp][r] + rg * ah[4 + tp][r]);
                float h = hst1[tp][r];
                float hN = ng + zg * (h - ng);
                hst1[tp][r] = hN;
                hv[r] = hN;
            }
            unsigned d0 = cvtpk(hv[0], hv[1]);
            unsigned d1 = cvtpk(hv[2], hv[3]);
            float g0 = bf2f((unsigned short)(d0 & 0xffffu));
            float g1 = bf2f((unsigned short)(d0 >> 16));
            float g2 = bf2f((unsigned short)(d1 & 0xffffu));
            float g3 = bf2f((unsigned short)(d1 >> 16));
            unsigned e0 = cvtpk(hv[0] - g0, hv[1] - g1);
            unsigned e1 = cvtpk(hv[2] - g2, hv[3] - g3);
            const int off = c * 80 + (16 * tp + 4 * q) * 2;
            uint2v wh = {d0, d1};
            uint2v wl = {e0, e1};
            *(uint2v*)(S1HI + off) = wh;
            *(uint2v*)(S1LO + off) = wl;
        }
    }

    // ---------------- epilogue: out = (h2 @ Wfc2^T + bfc2) @ Wfc^T + bfc ----
    // W_eff[k] = sum_j Wfc[j] * Wfc2[j][k]; out[b] = sum_k W_eff[k]*h2[b][k] + cst
    float acc = 0.0f;
#pragma unroll
    for (int tp = 0; tp < 2; ++tp) {
#pragma unroll
        for (int r = 0; r < 4; ++r) {
            const int k = 16 * tp + 4 * q + r;
            float we = 0.0f;
            for (int j = 0; j < 32; ++j)
                we += Wfc[j] * Wfc2[j * 32 + k];
            acc += we * hst1[tp][r];
        }
    }
    acc += __shfl_xor(acc, 16);
    acc += __shfl_xor(acc, 32);
    if (lane < 16) {
        float cst = bfc[0];
        for (int j = 0; j < 32; ++j)
            cst += Wfc[j] * bfc2[j];
        out[b0 + c] = acc + cst;
    }
}

extern "C" void kernel_launch(void* const* d_in, const int* in_sizes, int n_in,
                              void* d_out, int out_size, void* d_ws, size_t ws_size,
                              hipStream_t stream) {
    const float* x    = (const float*)d_in[0];
    const float* Wih0 = (const float*)d_in[1];
    const float* Whh0 = (const float*)d_in[2];
    const float* bih0 = (const float*)d_in[3];
    const float* bhh0 = (const float*)d_in[4];
    const float* Wih1 = (const float*)d_in[5];
    const float* Whh1 = (const float*)d_in[6];
    const float* bih1 = (const float*)d_in[7];
    const float* bhh1 = (const float*)d_in[8];
    const float* Wfc2 = (const float*)d_in[9];
    const float* bfc2 = (const float*)d_in[10];
    const float* Wfc  = (const float*)d_in[11];
    const float* bfc  = (const float*)d_in[12];

    const int nblocks = out_size / 16;  // 4096/16 = 256 groups of 16 batch rows
    hipLaunchKernelGGL(gru_fused, dim3(nblocks), dim3(64), 0, stream,
                       x, Wih0, Whh0, bih0, bhh0, Wih1, Whh1, bih1, bhh1,
                       Wfc2, bfc2, Wfc, bfc, (float*)d_out);
}

// Round 2
// 374.411 us; speedup vs baseline: 2.1464x; 2.1464x over previous
//
#include <hip/hip_runtime.h>

// 2-layer GRU (B=4096, S=512, IN=4, H=32) + FC(32->32) + FC(32->1), fp32 in/out.
// 4 waves/block: (layer L, unit-half hf). Layer pipeline with 1-step lag,
// unit halves split by MFMA tile (units [16h,16h+16) = tiles {h,2+h,4+h}).
// MFMA 16x16x32 bf16 with hi/lo split operands (~fp32 accuracy).
// State transported via double-buffered LDS; one barrier per step.

#define SEQ 512
#define LOG2E 1.44269504088896340736f

typedef __attribute__((ext_vector_type(8))) short  short8;
typedef __attribute__((ext_vector_type(4))) float  f32x4;
typedef __attribute__((ext_vector_type(2))) unsigned uint2v;

__device__ __forceinline__ unsigned short f2bf(float f) {
    unsigned u = __builtin_bit_cast(unsigned, f);
    return (unsigned short)((u + 0x7fffu + ((u >> 16) & 1u)) >> 16);
}
__device__ __forceinline__ float bf2f(unsigned short b) {
    return __builtin_bit_cast(float, ((unsigned)b) << 16);
}
__device__ __forceinline__ unsigned cvtpk(float a, float b) {
    unsigned r;
    asm("v_cvt_pk_bf16_f32 %0, %1, %2" : "=v"(r) : "v"(a), "v"(b));
    return r;
}
__device__ __forceinline__ float sigm(float x) {
    return __builtin_amdgcn_rcpf(1.0f + __builtin_amdgcn_exp2f(-LOG2E * x));
}
__device__ __forceinline__ float tanh_(float x) {
    return 1.0f - 2.0f * __builtin_amdgcn_rcpf(1.0f + __builtin_amdgcn_exp2f((2.0f * LOG2E) * x));
}

#define MFMA(A, B, C) __builtin_amdgcn_mfma_f32_16x16x32_bf16((A), (B), (C), 0, 0, 0)

__global__ __launch_bounds__(256, 1) void gru_fused(
    const float* __restrict__ x,
    const float* __restrict__ Wih0, const float* __restrict__ Whh0,
    const float* __restrict__ bih0, const float* __restrict__ bhh0,
    const float* __restrict__ Wih1, const float* __restrict__ Whh1,
    const float* __restrict__ bih1, const float* __restrict__ bhh1,
    const float* __restrict__ Wfc2, const float* __restrict__ bfc2,
    const float* __restrict__ Wfc,  const float* __restrict__ bfc,
    float* __restrict__ out)
{
    const int tid  = threadIdx.x;
    const int lane = tid & 63;
    const int wid  = tid >> 6;      // 0..3
    const int L    = wid >> 1;      // layer
    const int hf   = wid & 1;       // unit half: units [16*hf, 16*hf+16)
    const int c    = lane & 15;     // batch col
    const int q    = lane >> 4;     // 0..3
    const int b0   = blockIdx.x * 16;

    // LDS: H0 state/output of layer0: 2 bufs x {hi,lo} x [16 rows][80B].
    //      H2 state of layer1: same. Epilogue scratch: 32 floats.
    // region(buf,hilo) = (buf*2+hilo)*1280
    __shared__ __align__(16) char smem[10240 + 128];
    char* H0 = smem;
    char* H2 = smem + 5120;
    float* EP = (float*)(smem + 10240);

    // zero LDS state buffers (h0 = 0 for both layers)
    for (int i = tid; i < 2560; i += 256) ((unsigned*)smem)[i] = 0u;

    // ------------- per-wave weight fragments (loop-invariant) -------------
    const float* Wih = L ? Wih1 : Wih0;
    const float* Whh = L ? Whh1 : Whh0;
    const float* bih = L ? bih1 : bih0;
    const float* bhh = L ? bhh1 : bhh0;

    short8 wxh[3], wxl[3], whh[3], whl[3];
    f32x4 bx[3], bh[3];
    const int tts[3] = {hf, 2 + hf, 4 + hf};   // r,z,n tiles for this half

#pragma unroll
    for (int j = 0; j < 3; ++j) {
        const int t = tts[j];
        // hidden weights: 96x32, A-frag lane holds W[16t+c][8q+e]
        {
            const float* p = Whh + (16 * t + c) * 32 + 8 * q;
            f32x4 v0 = *(const f32x4*)p;
            f32x4 v1 = *(const f32x4*)(p + 4);
            short8 h8, l8;
#pragma unroll
            for (int e = 0; e < 8; ++e) {
                float v = (e < 4) ? v0[e] : v1[e - 4];
                unsigned short hb = f2bf(v);
                h8[e] = (short)hb;
                l8[e] = (short)f2bf(v - bf2f(hb));
            }
            whh[j] = h8;
            whl[j] = l8;
        }
        // input weights: layer0 is 96x4 (only k<4, q==0 lanes); layer1 is 96x32
        if (L == 0) {
            short8 h8 = {0, 0, 0, 0, 0, 0, 0, 0};
            short8 l8 = {0, 0, 0, 0, 0, 0, 0, 0};
            if (q == 0) {
                f32x4 v = *(const f32x4*)(Wih + (16 * t + c) * 4);
#pragma unroll
                for (int e = 0; e < 4; ++e) {
                    unsigned short hb = f2bf(v[e]);
                    h8[e] = (short)hb;
                    l8[e] = (short)f2bf(v[e] - bf2f(hb));
                }
            }
            wxh[j] = h8;
            wxl[j] = l8;
        } else {
            const float* p = Wih + (16 * t + c) * 32 + 8 * q;
            f32x4 v0 = *(const f32x4*)p;
            f32x4 v1 = *(const f32x4*)(p + 4);
            short8 h8, l8;
#pragma unroll
            for (int e = 0; e < 8; ++e) {
                float v = (e < 4) ? v0[e] : v1[e - 4];
                unsigned short hb = f2bf(v);
                h8[e] = (short)hb;
                l8[e] = (short)f2bf(v - bf2f(hb));
            }
            wxh[j] = h8;
            wxl[j] = l8;
        }
        // biases (D row = 4q+r within tile -> bias[16t+4q+r])
        bx[j] = *(const f32x4*)(bih + 16 * t + 4 * q);
        bh[j] = *(const f32x4*)(bhh + 16 * t + 4 * q);
    }

    float hst[4] = {0, 0, 0, 0};   // this wave's units 16hf+4q+r, batch c
    const float* xp = x + (long)(b0 + c) * (SEQ * 4);
    const int frag_off = c * 80 + q * 16;              // b128 B-frag read
    const int wr_off   = c * 80 + (16 * hf + 4 * q) * 2; // b64 D write

    __syncthreads();

    // ---------------- pipelined main loop: 513 iterations ----------------
    // iter i: L0 waves do step i (i<SEQ), L1 waves do step i-1 (i>=1).
    // L0: state read H0[(i+1)&1], write H0[i&1].
    // L1: input read H0[(i+1)&1], state read H2[i&1], write H2[(i+1)&1].
#pragma unroll 2
    for (int i = 0; i <= SEQ; ++i) {
        const bool act = (L == 0) ? (i < SEQ) : (i >= 1);
        if (act) {
            // input-side B fragment
            short8 uh, ul;
            if (L == 0) {
                short8 z8 = {0, 0, 0, 0, 0, 0, 0, 0};
                uh = z8; ul = z8;
                if (q == 0) {
                    f32x4 xv = *(const f32x4*)(xp + 4 * i);
#pragma unroll
                    for (int e = 0; e < 4; ++e) {
                        unsigned short hb = f2bf(xv[e]);
                        uh[e] = (short)hb;
                        ul[e] = (short)f2bf(xv[e] - bf2f(hb));
                    }
                }
            } else {
                char* src = H0 + ((i + 1) & 1) * 2560;
                uh = *(const short8*)(src + frag_off);
                ul = *(const short8*)(src + 1280 + frag_off);
            }
            // state-side B fragment
            char* st = (L == 0) ? (H0 + ((i + 1) & 1) * 2560)
                                : (H2 + (i & 1) * 2560);
            short8 sh = *(const short8*)(st + frag_off);
            short8 sl = *(const short8*)(st + 1280 + frag_off);

            f32x4 ax[3], ah[3];
#pragma unroll
            for (int j = 0; j < 3; ++j) {
                f32x4 a;
                a = MFMA(wxh[j], uh, bx[j]);
                a = MFMA(wxl[j], uh, a);
                a = MFMA(wxh[j], ul, a);
                ax[j] = a;
                f32x4 b;
                b = MFMA(whh[j], sh, bh[j]);
                b = MFMA(whl[j], sh, b);
                b = MFMA(whh[j], sl, b);
                ah[j] = b;
            }

            float hv[4];
#pragma unroll
            for (int r = 0; r < 4; ++r) {
                float rg = sigm(ax[0][r] + ah[0][r]);
                float zg = sigm(ax[1][r] + ah[1][r]);
                float ng = tanh_(ax[2][r] + rg * ah[2][r]);
                float hN = ng + zg * (hst[r] - ng);
                hst[r] = hN;
                hv[r] = hN;
            }
            unsigned d0 = cvtpk(hv[0], hv[1]);
            unsigned d1 = cvtpk(hv[2], hv[3]);
            float g0 = bf2f((unsigned short)(d0 & 0xffffu));
            float g1 = bf2f((unsigned short)(d0 >> 16));
            float g2 = bf2f((unsigned short)(d1 & 0xffffu));
            float g3 = bf2f((unsigned short)(d1 >> 16));
            unsigned e0 = cvtpk(hv[0] - g0, hv[1] - g1);
            unsigned e1 = cvtpk(hv[2] - g2, hv[3] - g3);

            char* dst = (L == 0) ? (H0 + (i & 1) * 2560)
                                 : (H2 + ((i + 1) & 1) * 2560);
            uint2v wh8 = {d0, d1};
            uint2v wl8 = {e0, e1};
            *(uint2v*)(dst + wr_off) = wh8;
            *(uint2v*)(dst + 1280 + wr_off) = wl8;
        }
        __syncthreads();
    }

    // ---------------- epilogue: out = Weff . h2 + cst ----------------
    if (L == 1) {
        float we[4] = {0, 0, 0, 0};
        const float* w2p = Wfc2 + 16 * hf + 4 * q;
#pragma unroll 8
        for (int j = 0; j < 32; ++j) {
            float wf = Wfc[j];
            f32x4 w2 = *(const f32x4*)(w2p + j * 32);
#pragma unroll
            for (int r = 0; r < 4; ++r) we[r] += wf * w2[r];
        }
        float acc = we[0] * hst[0] + we[1] * hst[1] + we[2] * hst[2] + we[3] * hst[3];
        acc += __shfl_xor(acc, 16);
        acc += __shfl_xor(acc, 32);
        if (q == 0) EP[hf * 16 + c] = acc;
    }
    __syncthreads();
    if (wid == 0 && q == 0) {
        float cst = bfc[0];
        for (int j = 0; j < 32; ++j) cst += Wfc[j] * bfc2[j];
        out[b0 + c] = EP[c] + EP[16 + c] + cst;
    }
}

extern "C" void kernel_launch(void* const* d_in, const int* in_sizes, int n_in,
                              void* d_out, int out_size, void* d_ws, size_t ws_size,
                              hipStream_t stream) {
    const float* x    = (const float*)d_in[0];
    const float* Wih0 = (const float*)d_in[1];
    const float* Whh0 = (const float*)d_in[2];
    const float* bih0 = (const float*)d_in[3];
    const float* bhh0 = (const float*)d_in[4];
    const float* Wih1 = (const float*)d_in[5];
    const float* Whh1 = (const float*)d_in[6];
    const float* bih1 = (const float*)d_in[7];
    const float* bhh1 = (const float*)d_in[8];
    const float* Wfc2 = (const float*)d_in[9];
    const float* bfc2 = (const float*)d_in[10];
    const float* Wfc  = (const float*)d_in[11];
    const float* bfc  = (const float*)d_in[12];

    const int nblocks = out_size / 16;  // 4096/16 = 256
    hipLaunchKernelGGL(gru_fused, dim3(nblocks), dim3(256), 0, stream,
                       x, Wih0, Whh0, bih0, bhh0, Wih1, Whh1, bih1, bhh1,
                       Wfc2, bfc2, Wfc, bfc, (float*)d_out);
}

// Round 3
// 353.803 us; speedup vs baseline: 2.2715x; 1.0582x over previous
//
#include <hip/hip_runtime.h>

// 2-layer GRU (B=4096, S=512, IN=4, H=32) + FC(32->32) + FC(32->1), fp32 in/out.
// 4 waves/block: (layer L, unit-half hf). Layer pipeline with 1-step lag.
// MFMA 16x16x32 bf16 hi/lo split (~fp32 accuracy), parallel depth<=2 chains.
// x bulk-staged through LDS 16 steps ahead (off critical path); L0 x-side
// computed as exact fp32 VALU FMAs. One barrier per step.

#define SEQ 512
#define LOG2E 1.44269504088896340736f

typedef __attribute__((ext_vector_type(8))) short  short8;
typedef __attribute__((ext_vector_type(4))) float  f32x4;
typedef __attribute__((ext_vector_type(2))) unsigned uint2v;

__device__ __forceinline__ unsigned short f2bf(float f) {
    unsigned u = __builtin_bit_cast(unsigned, f);
    return (unsigned short)((u + 0x7fffu + ((u >> 16) & 1u)) >> 16);
}
__device__ __forceinline__ float bf2f(unsigned short b) {
    return __builtin_bit_cast(float, ((unsigned)b) << 16);
}
__device__ __forceinline__ unsigned cvtpk(float a, float b) {
    unsigned r;
    asm("v_cvt_pk_bf16_f32 %0, %1, %2" : "=v"(r) : "v"(a), "v"(b));
    return r;
}
__device__ __forceinline__ float sigm(float x) {
    return __builtin_amdgcn_rcpf(1.0f + __builtin_amdgcn_exp2f(-LOG2E * x));
}
__device__ __forceinline__ float tanh_(float x) {
    return 1.0f - 2.0f * __builtin_amdgcn_rcpf(1.0f + __builtin_amdgcn_exp2f((2.0f * LOG2E) * x));
}

#define MFMA(A, B, C) __builtin_amdgcn_mfma_f32_16x16x32_bf16((A), (B), (C), 0, 0, 0)

// out = Ah*Bh + Al*Bh + Ah*Bl + bias, as two parallel chains (depth 2) + add.
__device__ __forceinline__ f32x4 side3(short8 Ah, short8 Al, short8 Bh, short8 Bl,
                                       f32x4 bias) {
    f32x4 zero = {0.0f, 0.0f, 0.0f, 0.0f};
    f32x4 p = MFMA(Ah, Bh, bias);
    f32x4 s = MFMA(Ah, Bl, zero);
    s = MFMA(Al, Bh, s);
    return p + s;
}

__global__ __launch_bounds__(256, 1) void gru_fused(
    const float* __restrict__ x,
    const float* __restrict__ Wih0, const float* __restrict__ Whh0,
    const float* __restrict__ bih0, const float* __restrict__ bhh0,
    const float* __restrict__ Wih1, const float* __restrict__ Whh1,
    const float* __restrict__ bih1, const float* __restrict__ bhh1,
    const float* __restrict__ Wfc2, const float* __restrict__ bfc2,
    const float* __restrict__ Wfc,  const float* __restrict__ bfc,
    float* __restrict__ out)
{
    const int tid  = threadIdx.x;
    const int lane = tid & 63;
    const int wid  = tid >> 6;      // 0..3
    const int L    = wid >> 1;      // layer
    const int hf   = wid & 1;       // unit half: units [16*hf, 16*hf+16)
    const int c    = lane & 15;     // batch col
    const int q    = lane >> 4;     // 0..3
    const int b0   = blockIdx.x * 16;

    // LDS: H0 (layer0 out) 2 bufs x {hi,lo} x [16][80B] = 5120
    //      H2 (layer1 state) same = 5120
    //      XS: x stage, 32 steps x 16 rows x 16B = 8192
    //      EP: epilogue scratch 128B
    __shared__ __align__(16) char smem[18688];
    char*  H0 = smem;
    char*  H2 = smem + 5120;
    f32x4* XS = (f32x4*)(smem + 10240);
    float* EP = (float*)(smem + 18432);

    // zero LDS state buffers (h0 = 0 for both layers)
    for (int i = tid; i < 2560; i += 256) ((unsigned*)smem)[i] = 0u;

    // ------------- per-wave weight fragments (loop-invariant) -------------
    const float* Whh = L ? Whh1 : Whh0;
    const float* bhh = L ? bhh1 : bhh0;
    const int tts[3] = {hf, 2 + hf, 4 + hf};   // r,z,n tiles for this half

    short8 wxh[3], wxl[3], whh[3], whl[3];
    f32x4  bx[3], bh[3];
    f32x4  wx0[12];      // L0 only: Wih0 rows (fp32 exact)
    float  bx0s[12];     // L0 only: bih0

#pragma unroll
    for (int j = 0; j < 3; ++j) {
        const int t = tts[j];
        // hidden weights: 96x32, A-frag lane holds W[16t+c][8q+e]
        {
            const float* p = Whh + (16 * t + c) * 32 + 8 * q;
            f32x4 v0 = *(const f32x4*)p;
            f32x4 v1 = *(const f32x4*)(p + 4);
            short8 h8, l8;
#pragma unroll
            for (int e = 0; e < 8; ++e) {
                float v = (e < 4) ? v0[e] : v1[e - 4];
                unsigned short hb = f2bf(v);
                h8[e] = (short)hb;
                l8[e] = (short)f2bf(v - bf2f(hb));
            }
            whh[j] = h8;
            whl[j] = l8;
        }
        bh[j] = *(const f32x4*)(bhh + 16 * t + 4 * q);
    }

    if (L == 0) {
        // x-side weights as fp32 scalars: row g = 16*tts[j] + 4q + r
#pragma unroll
        for (int j = 0; j < 3; ++j)
#pragma unroll
            for (int r = 0; r < 4; ++r) {
                const int g = 16 * tts[j] + 4 * q + r;
                wx0[4 * j + r]  = *(const f32x4*)(Wih0 + g * 4);
                bx0s[4 * j + r] = bih0[g];
            }
    } else {
        // u-side weights: Wih1 96x32 as A-frags
#pragma unroll
        for (int j = 0; j < 3; ++j) {
            const int t = tts[j];
            const float* p = Wih1 + (16 * t + c) * 32 + 8 * q;
            f32x4 v0 = *(const f32x4*)p;
            f32x4 v1 = *(const f32x4*)(p + 4);
            short8 h8, l8;
#pragma unroll
            for (int e = 0; e < 8; ++e) {
                float v = (e < 4) ? v0[e] : v1[e - 4];
                unsigned short hb = f2bf(v);
                h8[e] = (short)hb;
                l8[e] = (short)f2bf(v - bf2f(hb));
            }
            wxh[j] = h8;
            wxl[j] = l8;
            bx[j] = *(const f32x4*)(bih1 + 16 * t + 4 * q);
        }
    }

    // ------------- prologue: stage x steps 0..31 into LDS -------------
    {
        const int row = tid & 15;
        const int so  = tid >> 4;   // 0..15
#pragma unroll
        for (int k = 0; k < 2; ++k) {
            const int step = 16 * k + so;
            XS[step * 16 + row] =
                *(const f32x4*)(x + ((long)(b0 + row) * SEQ + step) * 4);
        }
    }

    float hst[4] = {0, 0, 0, 0};   // this wave's units 16hf+4q+r, batch c
    const int frag_off = c * 80 + q * 16;                 // b128 B-frag read
    const int wr_off   = c * 80 + (16 * hf + 4 * q) * 2;  // b64 D write

    __syncthreads();

    // ---------------- pipelined main loop: 513 iterations ----------------
    // iter i: L0 waves do step i (i<SEQ), L1 waves do step i-1 (i>=1).
#pragma unroll 2
    for (int i = 0; i <= SEQ; ++i) {
        // ---- bulk x staging: 16 steps, 16 iterations ahead ----
        if ((i & 15) == 0) {
            const int base = i + 16;
            if (base < SEQ) {
                const int row  = tid & 15;
                const int step = base + (tid >> 4);
                XS[(step & 31) * 16 + row] =
                    *(const f32x4*)(x + ((long)(b0 + row) * SEQ + step) * 4);
            }
        }

        const bool act = (L == 0) ? (i < SEQ) : (i >= 1);
        if (act) {
            // state-side B fragment (critical path — issue first)
            char* st = (L == 0) ? (H0 + ((i + 1) & 1) * 2560)
                                : (H2 + (i & 1) * 2560);
            short8 sh = *(const short8*)(st + frag_off);
            short8 sl = *(const short8*)(st + 1280 + frag_off);

            f32x4 ax[3], ah[3];
            if (L == 0) {
                // x-side: exact fp32 FMAs from LDS-staged x (off critical path)
                f32x4 xv = XS[(i & 31) * 16 + c];
#pragma unroll
                for (int j = 0; j < 3; ++j)
#pragma unroll
                    for (int r = 0; r < 4; ++r) {
                        f32x4 w = wx0[4 * j + r];
                        ax[j][r] = bx0s[4 * j + r] + w[0] * xv[0] + w[1] * xv[1]
                                 + w[2] * xv[2] + w[3] * xv[3];
                    }
            } else {
                char* us = H0 + ((i + 1) & 1) * 2560;
                short8 uh = *(const short8*)(us + frag_off);
                short8 ul = *(const short8*)(us + 1280 + frag_off);
#pragma unroll
                for (int j = 0; j < 3; ++j)
                    ax[j] = side3(wxh[j], wxl[j], uh, ul, bx[j]);
            }
#pragma unroll
            for (int j = 0; j < 3; ++j)
                ah[j] = side3(whh[j], whl[j], sh, sl, bh[j]);

            float hv[4];
#pragma unroll
            for (int r = 0; r < 4; ++r) {
                float rg = sigm(ax[0][r] + ah[0][r]);
                float zg = sigm(ax[1][r] + ah[1][r]);
                float ng = tanh_(ax[2][r] + rg * ah[2][r]);
                float hN = ng + zg * (hst[r] - ng);
                hst[r] = hN;
                hv[r] = hN;
            }
            unsigned d0 = cvtpk(hv[0], hv[1]);
            unsigned d1 = cvtpk(hv[2], hv[3]);
            float g0 = bf2f((unsigned short)(d0 & 0xffffu));
            float g1 = bf2f((unsigned short)(d0 >> 16));
            float g2 = bf2f((unsigned short)(d1 & 0xffffu));
            float g3 = bf2f((unsigned short)(d1 >> 16));
            unsigned e0 = cvtpk(hv[0] - g0, hv[1] - g1);
            unsigned e1 = cvtpk(hv[2] - g2, hv[3] - g3);

            char* dst = (L == 0) ? (H0 + (i & 1) * 2560)
                                 : (H2 + ((i + 1) & 1) * 2560);
            uint2v wh8 = {d0, d1};
            uint2v wl8 = {e0, e1};
            *(uint2v*)(dst + wr_off) = wh8;
            *(uint2v*)(dst + 1280 + wr_off) = wl8;
        }
        __syncthreads();
    }

    // ---------------- epilogue: out = Weff . h2 + cst ----------------
    if (L == 1) {
        float we[4] = {0, 0, 0, 0};
        const float* w2p = Wfc2 + 16 * hf + 4 * q;
#pragma unroll 8
        for (int j = 0; j < 32; ++j) {
            float wf = Wfc[j];
            f32x4 w2 = *(const f32x4*)(w2p + j * 32);
#pragma unroll
            for (int r = 0; r < 4; ++r) we[r] += wf * w2[r];
        }
        float acc = we[0] * hst[0] + we[1] * hst[1] + we[2] * hst[2] + we[3] * hst[3];
        acc += __shfl_xor(acc, 16);
        acc += __shfl_xor(acc, 32);
        if (q == 0) EP[hf * 16 + c] = acc;
    }
    __syncthreads();
    if (wid == 0 && q == 0) {
        float cst = bfc[0];
        for (int j = 0; j < 32; ++j) cst += Wfc[j] * bfc2[j];
        out[b0 + c] = EP[c] + EP[16 + c] + cst;
    }
}

extern "C" void kernel_launch(void* const* d_in, const int* in_sizes, int n_in,
                              void* d_out, int out_size, void* d_ws, size_t ws_size,
                              hipStream_t stream) {
    const float* x    = (const float*)d_in[0];
    const float* Wih0 = (const float*)d_in[1];
    const float* Whh0 = (const float*)d_in[2];
    const float* bih0 = (const float*)d_in[3];
    const float* bhh0 = (const float*)d_in[4];
    const float* Wih1 = (const float*)d_in[5];
    const float* Whh1 = (const float*)d_in[6];
    const float* bih1 = (const float*)d_in[7];
    const float* bhh1 = (const float*)d_in[8];
    const float* Wfc2 = (const float*)d_in[9];
    const float* bfc2 = (const float*)d_in[10];
    const float* Wfc  = (const float*)d_in[11];
    const float* bfc  = (const float*)d_in[12];

    const int nblocks = out_size / 16;  // 4096/16 = 256
    hipLaunchKernelGGL(gru_fused, dim3(nblocks), dim3(256), 0, stream,
                       x, Wih0, Whh0, bih0, bhh0, Wih1, Whh1, bih1, bhh1,
                       Wfc2, bfc2, Wfc, bfc, (float*)d_out);
}